// Round 2
// baseline (1388.262 us; speedup 1.0000x reference)
//
#include <hip/hip_runtime.h>

// DTNN message passing, fused single kernel.
// One wave = one node: M=32 neighbor-rows, H=O=128.
// All GEMMs via v_mfma_f32_32x32x16_bf16 in "transposed" orientation so the
// C/D layout (col=lane&31 = m) feeds the next GEMM's A operand via a single
// lane^32 half-swap (no LDS round-trip for the P matrix).

typedef __attribute__((ext_vector_type(8))) short short8;
typedef __attribute__((ext_vector_type(16))) float float16;

union Frag {
    short8 s;
    unsigned u[4];
    uint4 v;
};

// round-to-nearest-even fp32 -> bf16 (bit-level; inputs here are finite)
static __device__ __forceinline__ unsigned bf16_rn(float x) {
    unsigned u = __builtin_bit_cast(unsigned, x);
    return (u + 0x7fffu + ((u >> 16) & 1u)) >> 16;
}
static __device__ __forceinline__ unsigned pack2(float a, float b) {
    return bf16_rn(a) | (bf16_rn(b) << 16);
}
static __device__ __forceinline__ float unpk_lo(unsigned u) {
    return __builtin_bit_cast(float, u << 16);
}
static __device__ __forceinline__ float unpk_hi(unsigned u) {
    return __builtin_bit_cast(float, u & 0xffff0000u);
}
static __device__ __forceinline__ float tanh_fast(float x) {
    x = fminf(fmaxf(x, -15.0f), 15.0f);
    float e = __expf(2.0f * x);
    return (e - 1.0f) * __builtin_amdgcn_rcpf(e + 1.0f);
}

__global__ __launch_bounds__(256) void dtnn_kernel(
    const float* __restrict__ src_h, const float* __restrict__ he,
    const float* __restrict__ Wcf_w, const float* __restrict__ Wcf_b,
    const float* __restrict__ Wdf_w, const float* __restrict__ Wdf_b,
    const float* __restrict__ Wfc_w, const float* __restrict__ Wfc_b,
    float* __restrict__ out, int n_nodes)
{
    // 2 x [128 rows][16 x 16B units] bf16, XOR-swizzled at 16B granularity.
    // mat 0 = Wcf [h][a], mat 1 = Wfc [o][h].  Exactly 64 KB.
    __shared__ uint4 wlds[2][128][16];

    const int tid = threadIdx.x;

    // ---- stage weights global fp32 -> LDS bf16 (once per block) ----
    #pragma unroll
    for (int it = 0; it < 16; ++it) {
        int i = tid + 256 * it;          // 0..4095: 2 matrices x 2048 8-elem chunks
        int mat = i >> 11;               // wave-uniform per iteration
        int c = i & 2047;
        int r = c >> 4;                  // row 0..127
        int u = c & 15;                  // 16B unit within row
        const float* wsrc = (mat ? Wfc_w : Wcf_w) + r * 128 + u * 8;
        float4 lo = *(const float4*)(wsrc);
        float4 hi = *(const float4*)(wsrc + 4);
        uint4 p;
        p.x = pack2(lo.x, lo.y);
        p.y = pack2(lo.z, lo.w);
        p.z = pack2(hi.x, hi.y);
        p.w = pack2(hi.z, hi.w);
        wlds[mat][r][u ^ (r & 15)] = p;
    }
    __syncthreads();

    const int wave = tid >> 6;
    const int lane = tid & 63;
    const int ln = lane & 31;            // m-row (neighbor) / weight row
    const int q = lane >> 5;             // wave half

    const int n = blockIdx.x * 4 + wave;
    if (n >= n_nodes) return;

    // ---- Wdf fragments in registers: wdf[htile][kstep] ----
    Frag wdf[4][2];
    #pragma unroll
    for (int t = 0; t < 4; ++t) {
        #pragma unroll
        for (int s = 0; s < 2; ++s) {
            const float* p = Wdf_w + (32 * t + ln) * 32 + 16 * s + 8 * q;
            float4 lo = *(const float4*)p;
            float4 hi = *(const float4*)(p + 4);
            wdf[t][s].u[0] = pack2(lo.x, lo.y);
            wdf[t][s].u[1] = pack2(lo.z, lo.w);
            wdf[t][s].u[2] = pack2(hi.x, hi.y);
            wdf[t][s].u[3] = pack2(hi.z, hi.w);
        }
    }

    // ---- G2: X2^T[h][m] = Wdf * he^T + bdf ----
    // acc element r of tile t: h = (r&3) + 8*(r>>2) + 4q + 32t, col m = ln.
    float16 acc2[4];
    #pragma unroll
    for (int t = 0; t < 4; ++t) {
        #pragma unroll
        for (int g = 0; g < 4; ++g) {
            float4 b = *(const float4*)(Wdf_b + 32 * t + 8 * g + 4 * q);
            acc2[t][4 * g + 0] = b.x;
            acc2[t][4 * g + 1] = b.y;
            acc2[t][4 * g + 2] = b.z;
            acc2[t][4 * g + 3] = b.w;
        }
    }
    #pragma unroll
    for (int s = 0; s < 2; ++s) {
        const float* p = he + ((size_t)n * 32 + ln) * 32 + 16 * s + 8 * q;
        float4 lo = *(const float4*)p;
        float4 hi = *(const float4*)(p + 4);
        Frag bf;
        bf.u[0] = pack2(lo.x, lo.y);
        bf.u[1] = pack2(lo.z, lo.w);
        bf.u[2] = pack2(hi.x, hi.y);
        bf.u[3] = pack2(hi.z, hi.w);
        #pragma unroll
        for (int t = 0; t < 4; ++t)
            acc2[t] = __builtin_amdgcn_mfma_f32_32x32x16_bf16(wdf[t][s].s, bf.s, acc2[t], 0, 0, 0);
    }
    // pack X2^T to bf16 pairs (h-consecutive within each pair)
    unsigned x2p[4][8];
    #pragma unroll
    for (int t = 0; t < 4; ++t) {
        #pragma unroll
        for (int i = 0; i < 8; ++i)
            x2p[t][i] = pack2(acc2[t][2 * i], acc2[t][2 * i + 1]);
    }

    // ---- G1: X1^T[h][m] = Wcf * src_h^T + bcf ----
    float16 acc1[4];
    #pragma unroll
    for (int t = 0; t < 4; ++t) {
        #pragma unroll
        for (int g = 0; g < 4; ++g) {
            float4 b = *(const float4*)(Wcf_b + 32 * t + 8 * g + 4 * q);
            acc1[t][4 * g + 0] = b.x;
            acc1[t][4 * g + 1] = b.y;
            acc1[t][4 * g + 2] = b.z;
            acc1[t][4 * g + 3] = b.w;
        }
    }
    #pragma unroll
    for (int k8 = 0; k8 < 8; ++k8) {
        const float* p = src_h + ((size_t)n * 32 + ln) * 128 + 16 * k8 + 8 * q;
        float4 lo = *(const float4*)p;
        float4 hi = *(const float4*)(p + 4);
        Frag bf;
        bf.u[0] = pack2(lo.x, lo.y);
        bf.u[1] = pack2(lo.z, lo.w);
        bf.u[2] = pack2(hi.x, hi.y);
        bf.u[3] = pack2(hi.z, hi.w);
        #pragma unroll
        for (int t = 0; t < 4; ++t) {
            Frag w;
            w.v = wlds[0][32 * t + ln][(2 * k8 + q) ^ (ln & 15)];
            acc1[t] = __builtin_amdgcn_mfma_f32_32x32x16_bf16(w.s, bf.s, acc1[t], 0, 0, 0);
        }
    }

    // ---- P^T = X1^T .* X2^T, packed bf16 ----
    unsigned pp[4][8];
    #pragma unroll
    for (int t = 0; t < 4; ++t) {
        #pragma unroll
        for (int i = 0; i < 8; ++i) {
            float plo = acc1[t][2 * i] * unpk_lo(x2p[t][i]);
            float phi = acc1[t][2 * i + 1] * unpk_hi(x2p[t][i]);
            pp[t][i] = pack2(plo, phi);
        }
    }

    // ---- G3: Y[m][o] = P * Wfc^T + bfc ----
    // A operand: A[m=ln][k=h0+8q+j] built from pp via lane^32 half-swap.
    float16 acc3[4];
    #pragma unroll
    for (int ot = 0; ot < 4; ++ot) {
        float bv = Wfc_b[32 * ot + ln];   // o = 32*ot + ln (column index)
        #pragma unroll
        for (int r = 0; r < 16; ++r) acc3[ot][r] = bv;
    }
    #pragma unroll
    for (int s = 0; s < 8; ++s) {
        const int t = s >> 1;
        const int i0 = (s & 1) * 4;
        unsigned sw0 = (unsigned)__shfl_xor((int)pp[t][i0 + 0], 32, 64);
        unsigned sw1 = (unsigned)__shfl_xor((int)pp[t][i0 + 1], 32, 64);
        unsigned sw2 = (unsigned)__shfl_xor((int)pp[t][i0 + 2], 32, 64);
        unsigned sw3 = (unsigned)__shfl_xor((int)pp[t][i0 + 3], 32, 64);
        Frag a;
        a.u[0] = q ? sw2 : pp[t][i0 + 0];
        a.u[1] = q ? sw3 : pp[t][i0 + 1];
        a.u[2] = q ? pp[t][i0 + 2] : sw0;
        a.u[3] = q ? pp[t][i0 + 3] : sw1;
        #pragma unroll
        for (int ot = 0; ot < 4; ++ot) {
            Frag w;
            w.v = wlds[1][32 * ot + ln][(2 * s + q) ^ (ln & 15)];
            acc3[ot] = __builtin_amdgcn_mfma_f32_32x32x16_bf16(a.s, w.s, acc3[ot], 0, 0, 0);
        }
    }

    // ---- tanh + sum over the 32 neighbor rows, store ----
    #pragma unroll
    for (int ot = 0; ot < 4; ++ot) {
        float ssum = 0.0f;
        #pragma unroll
        for (int r = 0; r < 16; ++r) ssum += tanh_fast(acc3[ot][r]);
        ssum += __shfl_xor(ssum, 32, 64);        // other half holds the other 16 m-rows
        if (q == 0) out[(size_t)n * 128 + 32 * ot + ln] = ssum;
    }
}

extern "C" void kernel_launch(void* const* d_in, const int* in_sizes, int n_in,
                              void* d_out, int out_size, void* d_ws, size_t ws_size,
                              hipStream_t stream) {
    const float* src_h = (const float*)d_in[0];
    const float* he    = (const float*)d_in[1];
    const float* Wcf_w = (const float*)d_in[2];
    const float* Wcf_b = (const float*)d_in[3];
    const float* Wdf_w = (const float*)d_in[4];
    const float* Wdf_b = (const float*)d_in[5];
    const float* Wfc_w = (const float*)d_in[6];
    const float* Wfc_b = (const float*)d_in[7];
    float* out = (float*)d_out;

    const int n_nodes = in_sizes[0] / (32 * 128);
    const int blocks = (n_nodes + 3) / 4;   // 4 waves/block, 1 node/wave
    dtnn_kernel<<<blocks, 256, 0, stream>>>(src_h, he, Wcf_w, Wcf_b, Wdf_w, Wdf_b,
                                            Wfc_w, Wfc_b, out, n_nodes);
}